// Round 14
// baseline (39.542 us; speedup 1.0000x reference)
//
#include <hip/hip_runtime.h>
#include <hip/hip_bf16.h>

#define S_LEN 2048
#define DHEAD 128

typedef __bf16 bf16x8 __attribute__((ext_vector_type(8)));
typedef float  f32x16 __attribute__((ext_vector_type(16)));

union PK { __bf16 h[2]; unsigned u; };
union BW { unsigned w4[4]; bf16x8 v; };
union FU { float f; unsigned u; };

__device__ __forceinline__ bf16x8 cvt8(float4 a, float4 b) {
  bf16x8 r;
  r[0] = (__bf16)a.x; r[1] = (__bf16)a.y; r[2] = (__bf16)a.z; r[3] = (__bf16)a.w;
  r[4] = (__bf16)b.x; r[5] = (__bf16)b.y; r[6] = (__bf16)b.z; r[7] = (__bf16)b.w;
  return r;
}

#if __has_builtin(__builtin_amdgcn_exp2f)
__device__ __forceinline__ float exp2h(float x) { return __builtin_amdgcn_exp2f(x); }
#else
__device__ __forceinline__ float exp2h(float x) { return exp2f(x); }
#endif

// permlane32_swap: a' = {lo: a, hi: b_from_lane-32}; b' = {lo: a_from_lane+32, hi: b}
#if __has_builtin(__builtin_amdgcn_permlane32_swap)
__device__ __forceinline__ void plswap(unsigned &a, unsigned &b) {
  auto r = __builtin_amdgcn_permlane32_swap((int)a, (int)b, false, false);
  a = (unsigned)r[0];
  b = (unsigned)r[1];
}
#else
__device__ __forceinline__ void plswap(unsigned &a, unsigned &b) {
  const bool hi = (threadIdx.x & 32) != 0;
  const unsigned ea = (unsigned)__shfl_xor((int)a, 32);
  const unsigned eb = (unsigned)__shfl_xor((int)b, 32);
  const unsigned na = hi ? eb : a;
  const unsigned nb = hi ? b : ea;
  a = na; b = nb;
}
#endif
__device__ __forceinline__ float xmax32(float x) {
  FU a, b; a.f = x; b.f = x; plswap(a.u, b.u); return fmaxf(a.f, b.f);
}
__device__ __forceinline__ float xsum32(float x) {
  FU a, b; a.f = x; b.f = x; plswap(a.u, b.u); return a.f + b.f;
}

// -------- fused prepass: K and V fp32 -> fragment-ordered bf16 --------
// Kp chunk(b, t, ks, h, lq)[j] = K[b][32t+lq][16ks+8h+j]
//   byte = (b*64+t)*8192 + ks*1024 + h*512 + lq*16
// Vp chunk(b, u, db, s, h, lq)[j] = V[b][32u+16s+8h+j][32db+lq]
//   byte = (b*64+u)*8192 + (db*2+s)*1024 + h*512 + lq*16
__global__ __launch_bounds__(256) void kvprep(const float* __restrict__ K,
                                              const float* __restrict__ V,
                                              char* __restrict__ Kp,
                                              char* __restrict__ Vp, int nkb) {
  __shared__ float t[32 * 132];
  const int tid = threadIdx.x;
  if ((int)blockIdx.x < nkb) {
    const int bid = blockIdx.x;
    const int b = bid >> 6, tt = bid & 63;
    const int row = tid >> 3, c8 = tid & 7;
    const float4* src = (const float4*)(K + ((size_t)(b * S_LEN + 32 * tt + row) * DHEAD + 16 * c8));
    float4 f0 = src[0], f1 = src[1], f2 = src[2], f3 = src[3];
    char* dst = Kp + (size_t)(b * 64 + tt) * 8192 + c8 * 1024 + row * 16;
    *(bf16x8*)(dst)       = cvt8(f0, f1);   // h=0
    *(bf16x8*)(dst + 512) = cvt8(f2, f3);   // h=1
  } else {
    const int bid = blockIdx.x - nkb;
    const int b = bid >> 6, u = bid & 63;
    const int row = tid >> 3, c8 = tid & 7;
    const float4* src = (const float4*)(V + ((size_t)(b * S_LEN + 32 * u + row) * DHEAD + 16 * c8));
    float4 f0 = src[0], f1 = src[1], f2 = src[2], f3 = src[3];
    float* d = t + row * 132 + 16 * c8;
    *(float4*)(d) = f0; *(float4*)(d + 4) = f1;
    *(float4*)(d + 8) = f2; *(float4*)(d + 12) = f3;
    __syncthreads();
#pragma unroll
    for (int k = 0; k < 2; ++k) {
      const int id = tid * 2 + k;
      const int lq = id & 31, hh = (id >> 5) & 1, s = (id >> 6) & 1, db = (id >> 7) & 3;
      bf16x8 o;
#pragma unroll
      for (int j = 0; j < 8; ++j) o[j] = (__bf16)t[(16 * s + 8 * hh + j) * 132 + 32 * db + lq];
      *(bf16x8*)(Vp + (size_t)(b * 64 + u) * 8192 + id * 16) = o;
    }
  }
}

// -------- main: flash attention fwd, causal -------------------------------
// 512 threads = 8 waves, 64-row q-tile. Wave (qh,kq) = (w>>2, w&3):
// q rows [64T+32qh, +32), kv windows u = kq, kq+4, ... (32 keys each).
// The two waves sharing kq have IDENTICAL K/V streams on the same CU ->
// second wave's global loads hit L1 (2x reuse; halves L2 traffic).
// Grid 256 = 1 block/CU (8 waves = 2/SIMD). Barrier-free main loop;
// K double-buffered, V issued at window top (counted-vmcnt by issue order).
// S^T = mfma(K,Q) -> in-register softmax (exp2 domain) -> O^T = mfma(V^T,P^T).
// Per-q-half merge of 4 kv-parity partials in LDS at end.
// LDS overlay (fixed R13 overflow): Ob [0,67584), ml [67584,69632),
// Lbuf [69632,69888).
__global__ __launch_bounds__(512, 2) void attn_fwd(
    const float* __restrict__ Q, const char* __restrict__ Kp,
    const char* __restrict__ Vp, float* __restrict__ Out) {
  __shared__ __align__(16) char lds[69888];

  const int tid  = threadIdx.x;
  const int w    = tid >> 6;
  const int lane = tid & 63;
  const int h    = lane >> 5;
  const int lq   = lane & 31;
  const int qh   = w >> 2;     // q-half within the 64-row tile
  const int kq   = w & 3;      // kv quarter

  const int bi    = blockIdx.x;
  const int batch = bi & 7;    // XCD L2 locality
  const int T     = bi >> 3;   // 0..31, q rows [64T, 64T+64)
  const int q0g   = (T << 6) + (qh << 5);   // this wave's 32-row base
  const int ul    = 2 * T + qh;             // last kv window index (diagonal)

  const float* Qb = Q + (size_t)batch * S_LEN * DHEAD;
  const char*  Kb = Kp + (size_t)batch * (S_LEN * 256) + h * 512 + lq * 16;
  const char*  Vb = Vp + (size_t)batch * (S_LEN * 256) + h * 512 + lq * 16;

  float  mrun = -INFINITY, lrun = 0.f;
  f32x16 ob[4];
#pragma unroll
  for (int db = 0; db < 4; ++db)
#pragma unroll
    for (int r = 0; r < 16; ++r) ob[db][r] = 0.f;

  if (kq <= ul) {
    bf16x8 kfA[8], kfB[8];

    // ---- first-window K issued FIRST (Q processing covers its latency) ----
#pragma unroll
    for (int c = 0; c < 8; ++c) kfA[c] = *(const bf16x8*)(Kb + kq * 8192 + c * 1024);

    // ---- Q fragments, pre-scaled by (1/sqrt(D))*log2(e)  [exp2 domain] ----
    const float scale = 0.12751777903743892f;
    bf16x8 qf[8];
    {
      const float* qp = Qb + (size_t)(q0g + lq) * DHEAD + 8 * h;
#pragma unroll
      for (int ks = 0; ks < 8; ++ks) {
        float4 a = *(const float4*)(qp + 16 * ks);
        float4 b = *(const float4*)(qp + 16 * ks + 4);
        a.x *= scale; a.y *= scale; a.z *= scale; a.w *= scale;
        b.x *= scale; b.y *= scale; b.z *= scale; b.w *= scale;
        qf[ks] = cvt8(a, b);
      }
    }

    // one kv window: V(u) + K(next) issued up front, then QK(kcur) -> softmax
    // -> PV(vf). PV's waitcnt is vmcnt(8) (knxt keeps flying).
    auto window = [&](bf16x8 (&kcur)[8], bf16x8 (&knxt)[8], int u) {
      // ---- issue V for THIS window (oldest -> PV waits only these) ----
      bf16x8 vf[8];
      const char* vb = Vb + u * 8192;
#pragma unroll
      for (int c = 0; c < 8; ++c) vf[c] = *(const bf16x8*)(vb + c * 1024);
      // ---- issue next-window K (newest -> stays in flight past PV) ----
      const int tn = (u + 4 <= ul) ? (u + 4) : ul;
#pragma unroll
      for (int c = 0; c < 8; ++c) knxt[c] = *(const bf16x8*)(Kb + tn * 8192 + c * 1024);
      __builtin_amdgcn_sched_barrier(0);   // pin issue order ahead of QK

      // ---- S^T = K * Q^T ----
      f32x16 sa, sb;
#pragma unroll
      for (int r = 0; r < 16; ++r) { sa[r] = 0.f; sb[r] = 0.f; }
      __builtin_amdgcn_s_setprio(1);
#pragma unroll
      for (int ks = 0; ks < 4; ++ks)
        sa = __builtin_amdgcn_mfma_f32_32x32x16_bf16(kcur[ks], qf[ks], sa, 0, 0, 0);
#pragma unroll
      for (int ks = 4; ks < 8; ++ks)
        sb = __builtin_amdgcn_mfma_f32_32x32x16_bf16(kcur[ks], qf[ks], sb, 0, 0, 0);
      __builtin_amdgcn_s_setprio(0);

      float sv[16];
#pragma unroll
      for (int r = 0; r < 16; ++r) sv[r] = sa[r] + sb[r];
      if (u == ul) {                      // diagonal mask
#pragma unroll
        for (int r = 0; r < 16; ++r) {
          const int kvr = (r & 3) + 8 * (r >> 2) + 4 * h;
          if (kvr > lq) sv[r] = -INFINITY;
        }
      }

      // ---- in-register softmax: pairwise trees + permlane cross-half ----
      float m8[8];
#pragma unroll
      for (int r = 0; r < 8; ++r) m8[r] = fmaxf(sv[r], sv[r + 8]);
#pragma unroll
      for (int r = 0; r < 4; ++r) m8[r] = fmaxf(m8[r], m8[r + 4]);
      float mx = fmaxf(fmaxf(m8[0], m8[1]), fmaxf(m8[2], m8[3]));
      mx = xmax32(mx);

      if (__any(mx > mrun + 12.f)) {      // T13 defer-max (log2 units)
        const float mnew = fmaxf(mrun, mx);
        const float al = exp2h(mrun - mnew);
        lrun *= al;
#pragma unroll
        for (int db = 0; db < 4; ++db)
#pragma unroll
          for (int r = 0; r < 16; ++r) ob[db][r] *= al;
        mrun = mnew;
      }

      float pv[16];
#pragma unroll
      for (int r = 0; r < 16; ++r) pv[r] = exp2h(sv[r] - mrun);
      float s8[8];
#pragma unroll
      for (int r = 0; r < 8; ++r) s8[r] = pv[r] + pv[r + 8];
#pragma unroll
      for (int r = 0; r < 4; ++r) s8[r] = s8[r] + s8[r + 4];
      lrun += xsum32((s8[0] + s8[1]) + (s8[2] + s8[3]));

      // ---- P -> bf16 + half-wave exchange: 4 permlane32_swap (T12) ----
      unsigned cc[8];
#pragma unroll
      for (int i = 0; i < 8; ++i) {
        PK pk;
        pk.h[0] = (__bf16)pv[2 * i];
        pk.h[1] = (__bf16)pv[2 * i + 1];
        cc[i] = pk.u;
      }
      plswap(cc[0], cc[2]); plswap(cc[1], cc[3]);
      plswap(cc[4], cc[6]); plswap(cc[5], cc[7]);
      BW pb0, pb1;
      pb0.w4[0] = cc[0]; pb0.w4[1] = cc[1]; pb0.w4[2] = cc[2]; pb0.w4[3] = cc[3];
      pb1.w4[0] = cc[4]; pb1.w4[1] = cc[5]; pb1.w4[2] = cc[6]; pb1.w4[3] = cc[7];

      // ---- PV: O^T += V^T * P^T  (waits vf only; knxt stays in flight) ----
      __builtin_amdgcn_s_setprio(1);
#pragma unroll
      for (int db = 0; db < 4; ++db) {
        ob[db] = __builtin_amdgcn_mfma_f32_32x32x16_bf16(vf[2 * db],     pb0.v, ob[db], 0, 0, 0);
        ob[db] = __builtin_amdgcn_mfma_f32_32x32x16_bf16(vf[2 * db + 1], pb1.v, ob[db], 0, 0, 0);
      }
      __builtin_amdgcn_s_setprio(0);
    };

    int u = kq;
    while (true) {
      window(kfA, kfB, u);
      if (u + 4 > ul) break;
      u += 4;
      window(kfB, kfA, u);
      if (u + 4 > ul) break;
      u += 4;
    }
  }

  // ================= merge 4 kv-parity partials per q-half =================
  float2* ml   = (float2*)(lds + 67584);   // [67584, 69632)
  float*  Lbuf = (float*)(lds + 69632);    // [69632, 69888)
  char*   Obase = lds + qh * 33792;

  __syncthreads();   // all waves done with main loop (LDS about to be used)
  if (h == 0) ml[w * 32 + lq] = make_float2(mrun, lrun);
  __syncthreads();

  float M = -INFINITY;
#pragma unroll
  for (int ww = 0; ww < 4; ++ww) M = fmaxf(M, ml[(4 * qh + ww) * 32 + lq].x);
  float L = 0.f;
#pragma unroll
  for (int ww = 0; ww < 4; ++ww) {
    float2 v = ml[(4 * qh + ww) * 32 + lq];
    L += v.y * exp2h(v.x - M);
  }
  const float fw = exp2h(mrun - M);   // 0 for idle waves (mrun = -inf)
  if (kq == 0 && h == 0) Lbuf[32 * qh + lq] = 1.f / L;

  float* Ob = (float*)(Obase + (kq & 1) * 16896);
  if (kq < 2) {
#pragma unroll
    for (int db = 0; db < 4; ++db)
#pragma unroll
      for (int rr = 0; rr < 4; ++rr) {
        float4 val = { ob[db][4 * rr + 0] * fw, ob[db][4 * rr + 1] * fw,
                       ob[db][4 * rr + 2] * fw, ob[db][4 * rr + 3] * fw };
        *(float4*)(Ob + lq * 132 + 32 * db + 8 * rr + 4 * h) = val;
      }
  }
  __syncthreads();
  if (kq >= 2) {
#pragma unroll
    for (int db = 0; db < 4; ++db)
#pragma unroll
      for (int rr = 0; rr < 4; ++rr) {
        float* p = Ob + lq * 132 + 32 * db + 8 * rr + 4 * h;
        float4 cur = *(float4*)p;
        cur.x += ob[db][4 * rr + 0] * fw;
        cur.y += ob[db][4 * rr + 1] * fw;
        cur.z += ob[db][4 * rr + 2] * fw;
        cur.w += ob[db][4 * rr + 3] * fw;
        *(float4*)p = cur;
      }
  }
  __syncthreads();

  // ---- cooperative coalesced store: 64 rows x 128 cols ----
  const int row = tid >> 3;          // 0..63
  const int g   = row >> 5;
  const int lr  = row & 31;
  const int d0  = (tid & 7) * 16;
  const float inv = Lbuf[row];
  const float* O0 = (const float*)(lds + g * 33792);
  const float* O1 = (const float*)(lds + g * 33792 + 16896);
  float* orow = Out + ((size_t)(batch * S_LEN + (T << 6) + row)) * DHEAD + d0;
#pragma unroll
  for (int j = 0; j < 4; ++j) {
    float4 a = *(const float4*)(O0 + lr * 132 + d0 + 4 * j);
    float4 b = *(const float4*)(O1 + lr * 132 + d0 + 4 * j);
    float4 o = { (a.x + b.x) * inv, (a.y + b.y) * inv,
                 (a.z + b.z) * inv, (a.w + b.w) * inv };
    *(float4*)(orow + 4 * j) = o;
  }
}

extern "C" void kernel_launch(void* const* d_in, const int* in_sizes, int n_in,
                              void* d_out, int out_size, void* d_ws, size_t ws_size,
                              hipStream_t stream) {
  const float* q = (const float*)d_in[0];
  const float* k = (const float*)d_in[1];
  const float* v = (const float*)d_in[2];
  float* out = (float*)d_out;
  const int B = in_sizes[0] / (S_LEN * DHEAD);   // 8

  char* kp = (char*)d_ws;                                   // B * 512KB = 4 MB
  char* vp = (char*)d_ws + (size_t)B * S_LEN * 256;         // B * 512KB = 4 MB

  kvprep<<<dim3(B * 128), dim3(256), 0, stream>>>(k, v, kp, vp, B * 64);
  attn_fwd<<<dim3(B * (S_LEN / 64)), dim3(512), 0, stream>>>(q, kp, vp, out);
}

// Round 15
// 29.571 us; speedup vs baseline: 1.3372x; 1.3372x over previous
//
#include <hip/hip_runtime.h>
#include <hip/hip_bf16.h>

#define S_LEN 2048
#define DHEAD 128

typedef __bf16 bf16x8 __attribute__((ext_vector_type(8)));
typedef float  f32x16 __attribute__((ext_vector_type(16)));

union PK { __bf16 h[2]; unsigned u; };
union BW { unsigned w4[4]; bf16x8 v; };
union FU { float f; unsigned u; };

__device__ __forceinline__ bf16x8 cvt8(float4 a, float4 b) {
  bf16x8 r;
  r[0] = (__bf16)a.x; r[1] = (__bf16)a.y; r[2] = (__bf16)a.z; r[3] = (__bf16)a.w;
  r[4] = (__bf16)b.x; r[5] = (__bf16)b.y; r[6] = (__bf16)b.z; r[7] = (__bf16)b.w;
  return r;
}

#if __has_builtin(__builtin_amdgcn_exp2f)
__device__ __forceinline__ float exp2h(float x) { return __builtin_amdgcn_exp2f(x); }
#else
__device__ __forceinline__ float exp2h(float x) { return exp2f(x); }
#endif

// permlane32_swap: a' = {lo: a, hi: b_from_lane-32}; b' = {lo: a_from_lane+32, hi: b}
#if __has_builtin(__builtin_amdgcn_permlane32_swap)
__device__ __forceinline__ void plswap(unsigned &a, unsigned &b) {
  auto r = __builtin_amdgcn_permlane32_swap((int)a, (int)b, false, false);
  a = (unsigned)r[0];
  b = (unsigned)r[1];
}
#else
__device__ __forceinline__ void plswap(unsigned &a, unsigned &b) {
  const bool hi = (threadIdx.x & 32) != 0;
  const unsigned ea = (unsigned)__shfl_xor((int)a, 32);
  const unsigned eb = (unsigned)__shfl_xor((int)b, 32);
  const unsigned na = hi ? eb : a;
  const unsigned nb = hi ? b : ea;
  a = na; b = nb;
}
#endif
__device__ __forceinline__ float xmax32(float x) {
  FU a, b; a.f = x; b.f = x; plswap(a.u, b.u); return fmaxf(a.f, b.f);
}
__device__ __forceinline__ float xsum32(float x) {
  FU a, b; a.f = x; b.f = x; plswap(a.u, b.u); return a.f + b.f;
}

// -------- fused prepass: K and V fp32 -> fragment-ordered bf16 --------
// XCD-ALIGNED: batch = bid & 7, so the writer block runs on the same XCD
// (bid % 8) that the consumer attn block (bi & 7) reads from -> K/V stay in
// that XCD's L2 (1 MB working set vs 4 MB L2).
// Kp chunk(b, t, ks, h, lq)[j] = K[b][32t+lq][16ks+8h+j]
//   byte = (b*64+t)*8192 + ks*1024 + h*512 + lq*16
// Vp chunk(b, u, db, s, h, lq)[j] = V[b][32u+16s+8h+j][32db+lq]
//   byte = (b*64+u)*8192 + (db*2+s)*1024 + h*512 + lq*16
__global__ __launch_bounds__(256) void kvprep(const float* __restrict__ K,
                                              const float* __restrict__ V,
                                              char* __restrict__ Kp,
                                              char* __restrict__ Vp, int nkb) {
  __shared__ float t[32 * 132];
  const int tid = threadIdx.x;
  if ((int)blockIdx.x < nkb) {
    const int bid = blockIdx.x;
    const int b = bid & 7, tt = bid >> 3;
    const int row = tid >> 3, c8 = tid & 7;
    const float4* src = (const float4*)(K + ((size_t)(b * S_LEN + 32 * tt + row) * DHEAD + 16 * c8));
    float4 f0 = src[0], f1 = src[1], f2 = src[2], f3 = src[3];
    char* dst = Kp + (size_t)(b * 64 + tt) * 8192 + c8 * 1024 + row * 16;
    *(bf16x8*)(dst)       = cvt8(f0, f1);   // h=0
    *(bf16x8*)(dst + 512) = cvt8(f2, f3);   // h=1
  } else {
    const int bid = blockIdx.x - nkb;       // nkb = 512 ≡ 0 (mod 8): XCD map holds
    const int b = bid & 7, u = bid >> 3;
    const int row = tid >> 3, c8 = tid & 7;
    const float4* src = (const float4*)(V + ((size_t)(b * S_LEN + 32 * u + row) * DHEAD + 16 * c8));
    float4 f0 = src[0], f1 = src[1], f2 = src[2], f3 = src[3];
    float* d = t + row * 132 + 16 * c8;
    *(float4*)(d) = f0; *(float4*)(d + 4) = f1;
    *(float4*)(d + 8) = f2; *(float4*)(d + 12) = f3;
    __syncthreads();
#pragma unroll
    for (int k = 0; k < 2; ++k) {
      const int id = tid * 2 + k;
      const int lq = id & 31, hh = (id >> 5) & 1, s = (id >> 6) & 1, db = (id >> 7) & 3;
      bf16x8 o;
#pragma unroll
      for (int j = 0; j < 8; ++j) o[j] = (__bf16)t[(16 * s + 8 * hh + j) * 132 + 32 * db + lq];
      *(bf16x8*)(Vp + (size_t)(b * 64 + u) * 8192 + id * 16) = o;
    }
  }
}

// -------- main: flash attention fwd, causal -------------------------------
// 4 waves/block, 32 q rows, wave w owns kv windows u = w, w+4, ... (32 keys).
// Barrier-free main loop. K double-buffered (full-window lead); V issued at
// window top. Per-window order: exp -> pack -> PV (sum tree AFTER PV issue).
// S^T = mfma(K,Q) -> in-register softmax (exp2 domain, permlane cross-half)
// -> O^T = mfma(V^T, P^T). 4 kv-parity partials merged in LDS at end.
__global__ __launch_bounds__(256, 2) void attn_fwd(
    const float* __restrict__ Q, const char* __restrict__ Kp,
    const char* __restrict__ Vp, float* __restrict__ Out) {
  __shared__ __align__(16) char lds[38016];

  const int tid  = threadIdx.x;
  const int w    = tid >> 6;
  const int lane = tid & 63;
  const int h    = lane >> 5;
  const int lq   = lane & 31;

  const int bi    = blockIdx.x;
  const int batch = bi & 7;                                            // XCD L2 locality
  const int T     = (bi < 256) ? (63 - (bi >> 3)) : ((bi - 256) >> 3); // long tiles first
  const int q0    = T << 5;

  const float* Qb = Q + (size_t)batch * S_LEN * DHEAD;
  const char*  Kb = Kp + (size_t)batch * (S_LEN * 256) + h * 512 + lq * 16;
  const char*  Vb = Vp + (size_t)batch * (S_LEN * 256) + h * 512 + lq * 16;

  float  mrun = -INFINITY, lrun = 0.f;
  f32x16 ob[4];
#pragma unroll
  for (int db = 0; db < 4; ++db)
#pragma unroll
    for (int r = 0; r < 16; ++r) ob[db][r] = 0.f;

  if (w <= T) {
    bf16x8 kfA[8], kfB[8];

    // ---- first-window K issued FIRST (Q processing covers its latency) ----
#pragma unroll
    for (int c = 0; c < 8; ++c) kfA[c] = *(const bf16x8*)(Kb + w * 8192 + c * 1024);

    // ---- Q fragments, pre-scaled by (1/sqrt(D))*log2(e)  [exp2 domain] ----
    const float scale = 0.12751777903743892f;
    bf16x8 qf[8];
    {
      const float* qp = Qb + (size_t)(q0 + lq) * DHEAD + 8 * h;
#pragma unroll
      for (int ks = 0; ks < 8; ++ks) {
        float4 a = *(const float4*)(qp + 16 * ks);
        float4 b = *(const float4*)(qp + 16 * ks + 4);
        a.x *= scale; a.y *= scale; a.z *= scale; a.w *= scale;
        b.x *= scale; b.y *= scale; b.z *= scale; b.w *= scale;
        qf[ks] = cvt8(a, b);
      }
    }

    // one kv window: V(u) + K(next) issued up front, then QK(kcur) -> softmax
    // -> pack -> PV -> sums. PV's waitcnt is vmcnt(8) (knxt keeps flying).
    auto window = [&](bf16x8 (&kcur)[8], bf16x8 (&knxt)[8], int u) {
      // ---- issue V for THIS window (oldest -> PV waits only these) ----
      bf16x8 vf[8];
      const char* vb = Vb + u * 8192;
#pragma unroll
      for (int c = 0; c < 8; ++c) vf[c] = *(const bf16x8*)(vb + c * 1024);
      // ---- issue next-window K (newest -> stays in flight past PV) ----
      const int tn = (u + 4 <= T) ? (u + 4) : T;
#pragma unroll
      for (int c = 0; c < 8; ++c) knxt[c] = *(const bf16x8*)(Kb + tn * 8192 + c * 1024);
      __builtin_amdgcn_sched_barrier(0);   // pin issue order ahead of QK

      // ---- S^T = K * Q^T ----
      f32x16 sa, sb;
#pragma unroll
      for (int r = 0; r < 16; ++r) { sa[r] = 0.f; sb[r] = 0.f; }
      __builtin_amdgcn_s_setprio(1);
#pragma unroll
      for (int ks = 0; ks < 4; ++ks)
        sa = __builtin_amdgcn_mfma_f32_32x32x16_bf16(kcur[ks], qf[ks], sa, 0, 0, 0);
#pragma unroll
      for (int ks = 4; ks < 8; ++ks)
        sb = __builtin_amdgcn_mfma_f32_32x32x16_bf16(kcur[ks], qf[ks], sb, 0, 0, 0);
      __builtin_amdgcn_s_setprio(0);

      float sv[16];
#pragma unroll
      for (int r = 0; r < 16; ++r) sv[r] = sa[r] + sb[r];
      if (u == T) {                       // diagonal mask
#pragma unroll
        for (int r = 0; r < 16; ++r) {
          const int kvr = (r & 3) + 8 * (r >> 2) + 4 * h;
          if (kvr > lq) sv[r] = -INFINITY;
        }
      }

      // ---- in-register softmax: pairwise trees + permlane cross-half ----
      float m8[8];
#pragma unroll
      for (int r = 0; r < 8; ++r) m8[r] = fmaxf(sv[r], sv[r + 8]);
#pragma unroll
      for (int r = 0; r < 4; ++r) m8[r] = fmaxf(m8[r], m8[r + 4]);
      float mx = fmaxf(fmaxf(m8[0], m8[1]), fmaxf(m8[2], m8[3]));
      mx = xmax32(mx);

      if (__any(mx > mrun + 12.f)) {      // T13 defer-max (log2 units)
        const float mnew = fmaxf(mrun, mx);
        const float al = exp2h(mrun - mnew);
        lrun *= al;
#pragma unroll
        for (int db = 0; db < 4; ++db)
#pragma unroll
          for (int r = 0; r < 16; ++r) ob[db][r] *= al;
        mrun = mnew;
      }

      float pv[16];
#pragma unroll
      for (int r = 0; r < 16; ++r) pv[r] = exp2h(sv[r] - mrun);

      // ---- P -> bf16 + half-wave exchange FIRST (PV starts earlier) ----
      unsigned cc[8];
#pragma unroll
      for (int i = 0; i < 8; ++i) {
        PK pk;
        pk.h[0] = (__bf16)pv[2 * i];
        pk.h[1] = (__bf16)pv[2 * i + 1];
        cc[i] = pk.u;
      }
      plswap(cc[0], cc[2]); plswap(cc[1], cc[3]);
      plswap(cc[4], cc[6]); plswap(cc[5], cc[7]);
      BW pb0, pb1;
      pb0.w4[0] = cc[0]; pb0.w4[1] = cc[1]; pb0.w4[2] = cc[2]; pb0.w4[3] = cc[3];
      pb1.w4[0] = cc[4]; pb1.w4[1] = cc[5]; pb1.w4[2] = cc[6]; pb1.w4[3] = cc[7];

      // ---- PV: O^T += V^T * P^T  (waits vf only; knxt stays in flight) ----
      __builtin_amdgcn_s_setprio(1);
#pragma unroll
      for (int db = 0; db < 4; ++db) {
        ob[db] = __builtin_amdgcn_mfma_f32_32x32x16_bf16(vf[2 * db],     pb0.v, ob[db], 0, 0, 0);
        ob[db] = __builtin_amdgcn_mfma_f32_32x32x16_bf16(vf[2 * db + 1], pb1.v, ob[db], 0, 0, 0);
      }
      __builtin_amdgcn_s_setprio(0);

      // ---- row-sum AFTER PV issue (VALU overlaps MFMA pipe) ----
      float s8[8];
#pragma unroll
      for (int r = 0; r < 8; ++r) s8[r] = pv[r] + pv[r + 8];
#pragma unroll
      for (int r = 0; r < 4; ++r) s8[r] = s8[r] + s8[r + 4];
      lrun += xsum32((s8[0] + s8[1]) + (s8[2] + s8[3]));
    };

    int u = w;
    while (true) {
      window(kfA, kfB, u);
      if (u + 4 > T) break;
      u += 4;
      window(kfB, kfA, u);
      if (u + 4 > T) break;
      u += 4;
    }
  }

  // ================= merge 4 kv-parity partials =================
  float2* ml   = (float2*)(lds + 36864);
  float*  Lbuf = (float*)(lds + 37888);
  float*  Ob0  = (float*)(lds);
  float*  Ob1  = (float*)(lds + 16896);

  if (h == 0) ml[w * 32 + lq] = make_float2(mrun, lrun);
  __syncthreads();

  float M = -INFINITY;
#pragma unroll
  for (int ww = 0; ww < 4; ++ww) M = fmaxf(M, ml[ww * 32 + lq].x);
  float L = 0.f;
#pragma unroll
  for (int ww = 0; ww < 4; ++ww) {
    float2 v = ml[ww * 32 + lq];
    L += v.y * exp2h(v.x - M);
  }
  const float fw = exp2h(mrun - M);   // 0 for idle waves (mrun = -inf)
  if (w == 0 && h == 0) Lbuf[lq] = 1.f / L;

  float* Ob = (w & 1) ? Ob1 : Ob0;
  if (w < 2) {
#pragma unroll
    for (int db = 0; db < 4; ++db)
#pragma unroll
      for (int rr = 0; rr < 4; ++rr) {
        float4 val = { ob[db][4 * rr + 0] * fw, ob[db][4 * rr + 1] * fw,
                       ob[db][4 * rr + 2] * fw, ob[db][4 * rr + 3] * fw };
        *(float4*)(Ob + lq * 132 + 32 * db + 8 * rr + 4 * h) = val;
      }
  }
  __syncthreads();
  if (w >= 2) {
#pragma unroll
    for (int db = 0; db < 4; ++db)
#pragma unroll
      for (int rr = 0; rr < 4; ++rr) {
        float* p = Ob + lq * 132 + 32 * db + 8 * rr + 4 * h;
        float4 cur = *(float4*)p;
        cur.x += ob[db][4 * rr + 0] * fw;
        cur.y += ob[db][4 * rr + 1] * fw;
        cur.z += ob[db][4 * rr + 2] * fw;
        cur.w += ob[db][4 * rr + 3] * fw;
        *(float4*)p = cur;
      }
  }
  __syncthreads();

  // ---- cooperative coalesced store ----
  const int row = tid >> 3;
  const int d0  = (tid & 7) * 16;
  const float inv = Lbuf[row];
  float* orow = Out + ((size_t)(batch * S_LEN + q0 + row)) * DHEAD + d0;
#pragma unroll
  for (int j = 0; j < 4; ++j) {
    float4 a = *(float4*)(Ob0 + row * 132 + d0 + 4 * j);
    float4 b = *(float4*)(Ob1 + row * 132 + d0 + 4 * j);
    float4 o = { (a.x + b.x) * inv, (a.y + b.y) * inv,
                 (a.z + b.z) * inv, (a.w + b.w) * inv };
    *(float4*)(orow + 4 * j) = o;
  }
}

extern "C" void kernel_launch(void* const* d_in, const int* in_sizes, int n_in,
                              void* d_out, int out_size, void* d_ws, size_t ws_size,
                              hipStream_t stream) {
  const float* q = (const float*)d_in[0];
  const float* k = (const float*)d_in[1];
  const float* v = (const float*)d_in[2];
  float* out = (float*)d_out;
  const int B = in_sizes[0] / (S_LEN * DHEAD);   // 8

  char* kp = (char*)d_ws;                                   // B * 512KB = 4 MB
  char* vp = (char*)d_ws + (size_t)B * S_LEN * 256;         // B * 512KB = 4 MB

  kvprep<<<dim3(B * 128), dim3(256), 0, stream>>>(k, v, kp, vp, B * 64);
  attn_fwd<<<dim3(B * (S_LEN / 32)), dim3(256), 0, stream>>>(q, kp, vp, out);
}